// Round 2
// baseline (465.320 us; speedup 1.0000x reference)
//
#include <hip/hip_runtime.h>

#define F_IN 128
#define RDIM 128
#define KTOT 384   // 2*F_IN + RDIM
#define ALPHA 0.2f

// ---------- K0: w_i = a_i^T @ a_2  (three 128-vectors) ----------
__global__ __launch_bounds__(128) void k_wvec(const float* __restrict__ a,
                                              const float* __restrict__ a2,
                                              float* __restrict__ w1,
                                              float* __restrict__ w2,
                                              float* __restrict__ w3) {
  int k = threadIdx.x;  // 0..127
  float acc1 = 0.f, acc2 = 0.f, acc3 = 0.f;
  for (int f = 0; f < 128; ++f) {
    float s = a2[f];
    const float* row = a + (size_t)f * KTOT;
    acc1 += s * row[k];
    acc2 += s * row[128 + k];
    acc3 += s * row[256 + k];
  }
  w1[k] = acc1; w2[k] = acc2; w3[k] = acc3;
}

// ---------- K1: s1[n] = input[n]·w1, s2[n] = input[n]·w2 ----------
__global__ __launch_bounds__(256) void k_svec(const float* __restrict__ input,
                                              const float* __restrict__ w1,
                                              const float* __restrict__ w2,
                                              float* __restrict__ s1,
                                              float* __restrict__ s2, int N) {
  int lane = threadIdx.x & 63;
  int n = blockIdx.x * 4 + (threadIdx.x >> 6);
  if (n >= N) return;
  float2 x  = *(const float2*)(input + (size_t)n * F_IN + 2 * lane);
  float2 wa = *(const float2*)(w1 + 2 * lane);
  float2 wb = *(const float2*)(w2 + 2 * lane);
  float p1 = x.x * wa.x + x.y * wa.y;
  float p2 = x.x * wb.x + x.y * wb.y;
  #pragma unroll
  for (int m = 1; m < 64; m <<= 1) {
    p1 += __shfl_xor(p1, m, 64);
    p2 += __shfl_xor(p2, m, 64);
  }
  if (lane == 0) { s1[n] = p1; s2[n] = p2; }
}

// ---------- CSR build (edge rows are int32: edge[0..E-1]=src, edge[E..2E-1]=dst) ----------
__global__ __launch_bounds__(256) void k_hist(const int* __restrict__ edge_src,
                                              int* __restrict__ counts, int E) {
  int e = blockIdx.x * 256 + threadIdx.x;
  if (e < E) atomicAdd(&counts[edge_src[e]], 1);
}

__global__ __launch_bounds__(1024) void k_scan(const int* __restrict__ counts,
                                               int* __restrict__ row_ptr, int N) {
  __shared__ int part[1024];
  int t = threadIdx.x;
  int per = (N + 1023) / 1024;
  int b = t * per;
  int e = b + per; if (e > N) e = N;
  int s = 0;
  for (int i = b; i < e; ++i) s += counts[i];
  part[t] = s;
  __syncthreads();
  for (int off = 1; off < 1024; off <<= 1) {
    int v = (t >= off) ? part[t - off] : 0;
    __syncthreads();
    part[t] += v;
    __syncthreads();
  }
  int run = part[t] - s;  // exclusive base for this chunk
  for (int i = b; i < e; ++i) { row_ptr[i] = run; run += counts[i]; }
  if (t == 1023) row_ptr[N] = part[1023];
}

__global__ __launch_bounds__(256) void k_scatter(const int* __restrict__ edge_src,
                                                 const int* __restrict__ row_ptr,
                                                 int* __restrict__ cursor,
                                                 int* __restrict__ csr_eid, int E) {
  int e = blockIdx.x * 256 + threadIdx.x;
  if (e >= E) return;
  int src = edge_src[e];
  int pos = atomicAdd(&cursor[src], 1);
  csr_eid[row_ptr[src] + pos] = e;
}

// ---------- K3: per-node wave, atomic-free segment reduction ----------
// G[n] = [ (Σ ee*input[dst])/rs | (Σ ee*edge_embed[e])/rs ]  (256 floats)
__global__ __launch_bounds__(256) void k_edge(const float* __restrict__ input,
                                              const int* __restrict__ edge_dst,
                                              const float* __restrict__ edge_embed,
                                              const float* __restrict__ w3,
                                              const float* __restrict__ s1,
                                              const float* __restrict__ s2,
                                              const int* __restrict__ row_ptr,
                                              const int* __restrict__ csr_eid,
                                              float* __restrict__ G,
                                              float* __restrict__ rs, int N) {
  int lane = threadIdx.x & 63;
  int n = blockIdx.x * 4 + (threadIdx.x >> 6);
  if (n >= N) return;
  int beg = row_ptr[n], end = row_ptr[n + 1];
  float2 w3v = *(const float2*)(w3 + 2 * lane);
  float s1n = s1[n];
  float gix = 0.f, giy = 0.f, gex = 0.f, gey = 0.f, rsum = 0.f;
  int e_nxt = 0, d_nxt = 0;
  if (beg < end) { e_nxt = csr_eid[beg]; d_nxt = edge_dst[e_nxt]; }
  for (int i = beg; i < end; ++i) {
    int e = e_nxt, dst = d_nxt;
    if (i + 1 < end) { e_nxt = csr_eid[i + 1]; d_nxt = edge_dst[e_nxt]; }
    float2 x = *(const float2*)(edge_embed + (size_t)e * RDIM + 2 * lane);
    float2 y = *(const float2*)(input + (size_t)dst * F_IN + 2 * lane);
    float q = x.x * w3v.x + x.y * w3v.y;
    #pragma unroll
    for (int m = 1; m < 64; m <<= 1) q += __shfl_xor(q, m, 64);
    float s = s1n + s2[dst] + q;
    float lr = s > 0.f ? s : ALPHA * s;
    float ee = __expf(-lr);
    rsum += ee;
    gix += ee * y.x; giy += ee * y.y;
    gex += ee * x.x; gey += ee * x.y;
  }
  float scale = rsum > 0.f ? 1.f / rsum : 0.f;
  float* Gn = G + (size_t)n * 256;
  float2 o;
  o.x = gix * scale; o.y = giy * scale;
  *(float2*)(Gn + 2 * lane) = o;
  o.x = gex * scale; o.y = gey * scale;
  *(float2*)(Gn + 128 + 2 * lane) = o;
  if (lane == 0) rs[n] = rsum;
}

// ---------- K4: out = elu( [input | G] @ a^T ), zero rows where rs==0 ----------
__global__ __launch_bounds__(256) void k_out(const float* __restrict__ input,
                                             const float* __restrict__ G,
                                             const float* __restrict__ a,
                                             const float* __restrict__ rs,
                                             float* __restrict__ out, int N) {
  __shared__ float Xs[32][132];   // k-major, padded
  __shared__ float As[32][132];
  int t = threadIdx.x;
  int n0 = blockIdx.x * 128;
  int tx = t & 15, ty = t >> 4;   // 16 feat-groups x 16 node-groups (8 each)
  int r0 = t >> 3, c = t & 7;     // staging map
  float acc[8][8];
  #pragma unroll
  for (int i = 0; i < 8; ++i)
    #pragma unroll
    for (int j = 0; j < 8; ++j) acc[i][j] = 0.f;

  for (int k0 = 0; k0 < KTOT; k0 += 32) {
    #pragma unroll
    for (int pass = 0; pass < 4; ++pass) {
      int r = r0 + pass * 32;   // 0..127
      int n = n0 + r;
      float4 v = make_float4(0.f, 0.f, 0.f, 0.f);
      if (n < N) {
        if (k0 < 128) v = *(const float4*)(input + (size_t)n * 128 + k0 + 4 * c);
        else          v = *(const float4*)(G + (size_t)n * 256 + (k0 - 128) + 4 * c);
      }
      Xs[4 * c + 0][r] = v.x; Xs[4 * c + 1][r] = v.y;
      Xs[4 * c + 2][r] = v.z; Xs[4 * c + 3][r] = v.w;
      float4 w = *(const float4*)(a + (size_t)r * KTOT + k0 + 4 * c);
      As[4 * c + 0][r] = w.x; As[4 * c + 1][r] = w.y;
      As[4 * c + 2][r] = w.z; As[4 * c + 3][r] = w.w;
    }
    __syncthreads();
    #pragma unroll 4
    for (int kk = 0; kk < 32; ++kk) {
      float4 a0 = *(const float4*)&As[kk][8 * tx];
      float4 a1 = *(const float4*)&As[kk][8 * tx + 4];
      float4 x0 = *(const float4*)&Xs[kk][8 * ty];
      float4 x1 = *(const float4*)&Xs[kk][8 * ty + 4];
      float av[8] = {a0.x, a0.y, a0.z, a0.w, a1.x, a1.y, a1.z, a1.w};
      float xv[8] = {x0.x, x0.y, x0.z, x0.w, x1.x, x1.y, x1.z, x1.w};
      #pragma unroll
      for (int i = 0; i < 8; ++i)
        #pragma unroll
        for (int j = 0; j < 8; ++j) acc[i][j] += xv[i] * av[j];
    }
    __syncthreads();
  }
  #pragma unroll
  for (int i = 0; i < 8; ++i) {
    int n = n0 + 8 * ty + i;
    if (n >= N) continue;
    float rsv = rs[n];
    float o[8];
    #pragma unroll
    for (int j = 0; j < 8; ++j) {
      float v = acc[i][j];
      float h = v > 0.f ? v : (__expf(v) - 1.f);
      o[j] = (rsv == 0.f) ? 0.f : h;
    }
    float4* dstp = (float4*)(out + (size_t)n * 128 + 8 * tx);
    dstp[0] = make_float4(o[0], o[1], o[2], o[3]);
    dstp[1] = make_float4(o[4], o[5], o[6], o[7]);
  }
}

extern "C" void kernel_launch(void* const* d_in, const int* in_sizes, int n_in,
                              void* d_out, int out_size, void* d_ws, size_t ws_size,
                              hipStream_t stream) {
  const float* input      = (const float*)d_in[0];
  const int*   edge       = (const int*)d_in[1];   // int32! [2,E] row-major
  const float* edge_embed = (const float*)d_in[2];
  const float* a          = (const float*)d_in[3];
  const float* a_2        = (const float*)d_in[4];
  float* out = (float*)d_out;
  int N = in_sizes[0] / F_IN;
  int E = in_sizes[1] / 2;
  const int* edge_src = edge;
  const int* edge_dst = edge + E;

  char* p = (char*)d_ws;
  auto take = [&](size_t bytes) { char* q = p; p += (bytes + 255) & ~(size_t)255; return q; };
  float* w1      = (float*)take(128 * 4);
  float* w2      = (float*)take(128 * 4);
  float* w3      = (float*)take(128 * 4);
  float* s1      = (float*)take((size_t)N * 4);
  float* s2      = (float*)take((size_t)N * 4);
  float* rs      = (float*)take((size_t)N * 4);
  int*   counts  = (int*)take((size_t)N * 4);
  int*   row_ptr = (int*)take((size_t)(N + 1) * 4);
  int*   csr_eid = (int*)take((size_t)E * 4);
  float* G       = (float*)take((size_t)N * 256 * 4);

  hipMemsetAsync(counts, 0, (size_t)N * 4, stream);
  k_wvec<<<1, 128, 0, stream>>>(a, a_2, w1, w2, w3);
  k_svec<<<(N + 3) / 4, 256, 0, stream>>>(input, w1, w2, s1, s2, N);
  k_hist<<<(E + 255) / 256, 256, 0, stream>>>(edge_src, counts, E);
  k_scan<<<1, 1024, 0, stream>>>(counts, row_ptr, N);
  hipMemsetAsync(counts, 0, (size_t)N * 4, stream);
  k_scatter<<<(E + 255) / 256, 256, 0, stream>>>(edge_src, row_ptr, counts, csr_eid, E);
  k_edge<<<(N + 3) / 4, 256, 0, stream>>>(input, edge_dst, edge_embed, w3, s1, s2,
                                          row_ptr, csr_eid, G, rs, N);
  k_out<<<(N + 127) / 128, 256, 0, stream>>>(input, G, a, rs, out, N);
}